// Round 2
// 2745.027 us; speedup vs baseline: 1.2270x; 1.2270x over previous
//
#include <hip/hip_runtime.h>
#include <hip/hip_bf16.h>
#include <math.h>

#define D_   1024
#define H_   16
#define V_   50257
#define L_   4
#define B_   2
#define S_   1024
#define DK_  64
#define DFF_ 4096
#define NT_  (B_*S_)   // 2048 tokens

using bf16 = __hip_bfloat16;
typedef __attribute__((ext_vector_type(8))) __bf16 bf16x8;
typedef __attribute__((ext_vector_type(4))) float  f32x4;

// async global->LDS, 16B per lane; LDS dest is wave-uniform base + lane*16
__device__ __forceinline__ void gload_lds16(const void* g, void* l)
{
    __builtin_amdgcn_global_load_lds(
        (const __attribute__((address_space(1))) unsigned int*)g,
        (__attribute__((address_space(3))) unsigned int*)l, 16, 0, 0);
}

// ---------------------------------------------------------------------------
// Generic bf16 GEMM: C[M,N] = A[M,K] @ B^T  (B stored [N,K] row-major, i.e.
// K-contiguous on both operands). Optional: bias, scale, GELU, fp32 residual
// add, fp32 and/or bf16 outputs, batched via blockIdx.z = b1*bz2 + b2,
// causal tile skip (for attention scores), swapxy raster (m-fastest) for
// B-panel cache reuse on wide-N GEMMs (lm_head).
// Staging: global_load_lds dwordx4 into LINEAR LDS [rows][32] bf16 (m97
// structure, learn_hip m97/m151: ~874 TF @4096^3 vs ~646 reg-staged).
// Verified fragment layouts (learn_hip m89/m91/m97):
//   A-frag:  lane holds A[m = lane&15][k = (lane>>4)*8 + j]
//   B-frag:  lane holds B[n = lane&15][k = (lane>>4)*8 + j]   (B^T layout)
//   C/D:     col = lane&15, row = (lane>>4)*4 + reg
// Requires: M % BM == 0, K % 32 == 0 (N tail handled by clamp + store guard).
// ---------------------------------------------------------------------------
template<int BM, int BN>
__global__ __launch_bounds__(256) void gemm_bt(
    const bf16* __restrict__ A, int lda, long long sA1, long long sA2,
    const bf16* __restrict__ Bm, int ldb, long long sB1, long long sB2,
    const float* __restrict__ bias, float scale,
    const float* __restrict__ Rz, int ldr,
    float* __restrict__ CF, int ldcF, long long sCF1, long long sCF2,
    bf16* __restrict__ CB, int ldcB, long long sCB1, long long sCB2,
    int M, int N, int K, int bz2, int gelu_f, int causal, int swapxy)
{
    int bx = blockIdx.x, by = blockIdx.y;
    if (swapxy) { const int t = bx; bx = by; by = t; }
    const int m0 = by * BM;
    const int n0 = bx * BN;
    if (causal && n0 > m0 + BM - 1) return;   // fully-masked score tile, never read

    const int z  = blockIdx.z;
    const int b1 = z / bz2, b2 = z % bz2;
    A  += (long long)b1 * sA1 + (long long)b2 * sA2;
    Bm += (long long)b1 * sB1 + (long long)b2 * sB2;
    const long long cfoff = (long long)b1 * sCF1 + (long long)b2 * sCF2;
    const long long cboff = (long long)b1 * sCB1 + (long long)b2 * sCB2;

    // linear LDS: rows of 32 bf16 (64 B). global_load_lds writes base+lane*16.
    __shared__ __align__(16) bf16 As[BM * 32];
    __shared__ __align__(16) bf16 Bs[BN * 32];

    const int tid  = threadIdx.x;
    const int lane = tid & 63;
    const int wave = tid >> 6;
    const int wm = (wave >> 1) * 64;
    const int wn = (wave & 1) * (BN / 2);
    constexpr int WM = 4;
    constexpr int WN = (BN / 2) / 16;

    f32x4 acc[WM][WN] = {};

    const int lm = lane & 15;
    const int lk = (lane >> 4) * 8;

    // staging geometry: one wave-call covers 1024 B = 16 rows x 64 B.
    // lane i -> row (i>>2) within chunk, byte col (i&3)*16.
    const int lrow  = lane >> 2;         // 0..15
    const int lcolb = (lane & 3) * 16;   // 0/16/32/48 bytes

    constexpr int CA = BM / 16 / 4;      // A chunks per wave (BM=128 -> 2)
    constexpr int CB_ = BN / 16 / 4;     // B chunks per wave

    for (int k0 = 0; k0 < K; k0 += 32) {
        #pragma unroll
        for (int it = 0; it < CA; it++) {
            const int c = wave + it * 4;
            const char* src = (const char*)(A + (long long)(m0 + c * 16 + lrow) * lda + k0) + lcolb;
            gload_lds16(src, &As[c * 16 * 32]);
        }
        #pragma unroll
        for (int it = 0; it < CB_; it++) {
            const int c = wave + it * 4;
            int rr = n0 + c * 16 + lrow; rr = rr < N ? rr : N - 1;   // clamp (head: V=50257)
            const char* src = (const char*)(Bm + (long long)rr * ldb + k0) + lcolb;
            gload_lds16(src, &Bs[c * 16 * 32]);
        }
        __syncthreads();   // compiler emits s_waitcnt vmcnt(0) before s_barrier

        bf16x8 af[WM], bfr[WN];
        #pragma unroll
        for (int i = 0; i < WM; i++)
            af[i] = *(const bf16x8*)&As[(wm + i * 16 + lm) * 32 + lk];
        #pragma unroll
        for (int j = 0; j < WN; j++)
            bfr[j] = *(const bf16x8*)&Bs[(wn + j * 16 + lm) * 32 + lk];

        #pragma unroll
        for (int i = 0; i < WM; i++)
            #pragma unroll
            for (int j = 0; j < WN; j++)
                acc[i][j] = __builtin_amdgcn_mfma_f32_16x16x32_bf16(
                    af[i], bfr[j], acc[i][j], 0, 0, 0);
        __syncthreads();
    }

    const int rmb = (lane >> 4) << 2;
    #pragma unroll
    for (int i = 0; i < WM; i++) {
        #pragma unroll
        for (int j = 0; j < WN; j++) {
            const int n = n0 + wn + j * 16 + lm;
            if (n >= N) continue;
            const float bv = bias ? bias[n] : 0.0f;
            #pragma unroll
            for (int r = 0; r < 4; r++) {
                const int m = m0 + wm + i * 16 + rmb + r;
                float v = acc[i][j][r] * scale + bv;
                if (gelu_f) v = 0.5f * v * (1.0f + erff(v * 0.70710678118654752f));
                if (Rz) v += Rz[(long long)m * ldr + n];
                if (CF) CF[cfoff + (long long)m * ldcF + n] = v;
                if (CB) CB[cboff + (long long)m * ldcB + n] = __float2bfloat16(v);
            }
        }
    }
}

// fp32 [K,N] -> bf16 [N,K] (convert + transpose), dims multiples of 32
__global__ __launch_bounds__(256) void convT(const float* __restrict__ in,
                                             bf16* __restrict__ out, int K, int N)
{
    __shared__ float tile[32][33];
    const int bx = blockIdx.x * 32;   // N
    const int by = blockIdx.y * 32;   // K
    const int tx = threadIdx.x & 31, ty = threadIdx.x >> 5;
    #pragma unroll
    for (int i = 0; i < 32; i += 8)
        tile[ty + i][tx] = in[(long long)(by + ty + i) * N + bx + tx];
    __syncthreads();
    #pragma unroll
    for (int i = 0; i < 32; i += 8)
        out[(long long)(bx + ty + i) * K + by + tx] = __float2bfloat16(tile[tx][ty + i]);
}

// fp32 -> bf16 elementwise (n % 4 == 0)
__global__ __launch_bounds__(256) void conv_bf16(const float* __restrict__ in,
                                                 bf16* __restrict__ out, long long n)
{
    const long long i = ((long long)blockIdx.x * 256 + threadIdx.x) * 4;
    if (i >= n) return;
    const float4 v = *(const float4*)&in[i];
    union { bf16 h[4]; uint2 u; } o;
    o.h[0] = __float2bfloat16(v.x); o.h[1] = __float2bfloat16(v.y);
    o.h[2] = __float2bfloat16(v.z); o.h[3] = __float2bfloat16(v.w);
    *(uint2*)&out[i] = o.u;
}

// v [B,S,H*DK] bf16 -> vT [B*H, DK, S] bf16
__global__ __launch_bounds__(256) void transpose_v(const bf16* __restrict__ v,
                                                   bf16* __restrict__ vT)
{
    __shared__ bf16 tile[32][33];
    const int bh = blockIdx.z;
    const int b = bh >> 4, h = bh & 15;
    const int s0 = blockIdx.x * 32, d0 = blockIdx.y * 32;
    const int tx = threadIdx.x & 31, ty = threadIdx.x >> 5;
    const bf16* src = v + (long long)b * S_ * D_ + h * DK_;
    #pragma unroll
    for (int i = 0; i < 32; i += 8)
        tile[ty + i][tx] = src[(long long)(s0 + ty + i) * D_ + d0 + tx];
    __syncthreads();
    bf16* dst = vT + (long long)bh * DK_ * S_;
    #pragma unroll
    for (int i = 0; i < 32; i += 8)
        dst[(long long)(d0 + ty + i) * S_ + s0 + tx] = tile[tx][ty + i];
}

// x[t] = te[idx[t]] + pe[t % S]; writes fp32 x and bf16 xb
__global__ __launch_bounds__(64) void embed_kernel(const int* __restrict__ idx,
    const float* __restrict__ te, const float* __restrict__ pe,
    float* __restrict__ x, bf16* __restrict__ xb)
{
    const int t = blockIdx.x;
    const int s = t & (S_ - 1);
    const int id = idx[t];
    const float* tr = te + (long long)id * D_;
    const float* pr = pe + (long long)s * D_;
    float* xr  = x  + (long long)t * D_;
    bf16*  xbr = xb + (long long)t * D_;
    for (int i = threadIdx.x * 4; i < D_; i += 256) {
        const float4 a = *(const float4*)&tr[i];
        const float4 b = *(const float4*)&pr[i];
        const float4 c = {a.x + b.x, a.y + b.y, a.z + b.z, a.w + b.w};
        *(float4*)&xr[i] = c;
        union { bf16 h[4]; uint2 u; } o;
        o.h[0] = __float2bfloat16(c.x); o.h[1] = __float2bfloat16(c.y);
        o.h[2] = __float2bfloat16(c.z); o.h[3] = __float2bfloat16(c.w);
        *(uint2*)&xbr[i] = o.u;
    }
}

// one wave per row: bf16 layernorm(x fp32) -> out bf16
__global__ __launch_bounds__(64) void layernorm_kernel(const float* __restrict__ x,
    const float* __restrict__ g, const float* __restrict__ b, bf16* __restrict__ out)
{
    const int row = blockIdx.x;
    const float* xr = x + (long long)row * D_;
    float s = 0.f, ss = 0.f;
    for (int i = threadIdx.x * 4; i < D_; i += 256) {
        const float4 v = *(const float4*)&xr[i];
        s  += v.x + v.y + v.z + v.w;
        ss += v.x * v.x + v.y * v.y + v.z * v.z + v.w * v.w;
    }
    #pragma unroll
    for (int off = 32; off; off >>= 1) {
        s  += __shfl_down(s, off);
        ss += __shfl_down(ss, off);
    }
    s = __shfl(s, 0); ss = __shfl(ss, 0);
    const float mean = s * (1.0f / D_);
    const float var  = ss * (1.0f / D_) - mean * mean;
    const float rstd = rsqrtf(var + 1e-5f);
    bf16* orow = out + (long long)row * D_;
    for (int i = threadIdx.x * 4; i < D_; i += 256) {
        const float4 v = *(const float4*)&xr[i];
        union { bf16 h[4]; uint2 u; } o;
        o.h[0] = __float2bfloat16((v.x - mean) * rstd * g[i]     + b[i]);
        o.h[1] = __float2bfloat16((v.y - mean) * rstd * g[i + 1] + b[i + 1]);
        o.h[2] = __float2bfloat16((v.z - mean) * rstd * g[i + 2] + b[i + 2]);
        o.h[3] = __float2bfloat16((v.w - mean) * rstd * g[i + 3] + b[i + 3]);
        *(uint2*)&orow[i] = o.u;
    }
}

// one wave per (bh, sq) row: causal softmax, fp32 scores -> bf16 P (zeros past sq)
__global__ __launch_bounds__(64) void softmax_kernel(const float* __restrict__ sc,
                                                     bf16* __restrict__ P)
{
    const int sq = blockIdx.x;
    const long long base = ((long long)blockIdx.y * S_ + sq) * S_;
    const float* row = sc + base;
    bf16* prow = P + base;
    const int lane = threadIdx.x;
    const int len = sq + 1;
    float mx = -3.0e38f;
    for (int i = lane; i < len; i += 64) mx = fmaxf(mx, row[i]);
    #pragma unroll
    for (int off = 32; off; off >>= 1) mx = fmaxf(mx, __shfl_down(mx, off));
    mx = __shfl(mx, 0);
    float sum = 0.f;
    for (int i = lane; i < len; i += 64) sum += __expf(row[i] - mx);
    #pragma unroll
    for (int off = 32; off; off >>= 1) sum += __shfl_down(sum, off);
    sum = __shfl(sum, 0);
    const float inv = 1.0f / sum;
    for (int i = lane; i < S_; i += 64) {
        const float pv = (i < len) ? __expf(row[i] - mx) * inv : 0.f;
        prow[i] = __float2bfloat16(pv);
    }
}

__global__ void ws_fail_kernel(float* out) { out[0] = 12345.0f; }

extern "C" void kernel_launch(void* const* d_in, const int* in_sizes, int n_in,
                              void* d_out, int out_size, void* d_ws, size_t ws_size,
                              hipStream_t stream)
{
    const int*   idx  = (const int*)  d_in[0];
    const float* te   = (const float*)d_in[1];
    const float* pe   = (const float*)d_in[2];
    const float* wq   = (const float*)d_in[3];
    const float* bq   = (const float*)d_in[4];
    const float* wk   = (const float*)d_in[5];
    const float* bk   = (const float*)d_in[6];
    const float* wv   = (const float*)d_in[7];
    const float* bv   = (const float*)d_in[8];
    const float* wo   = (const float*)d_in[9];
    const float* bo   = (const float*)d_in[10];
    const float* ln2g = (const float*)d_in[11];
    const float* ln2b = (const float*)d_in[12];
    const float* w1   = (const float*)d_in[13];
    const float* b1   = (const float*)d_in[14];
    const float* w2   = (const float*)d_in[15];
    const float* b2   = (const float*)d_in[16];
    const float* lnfg = (const float*)d_in[17];
    const float* lnfb = (const float*)d_in[18];
    float* logits = (float*)d_out;

    char* p = (char*)d_ws;
    auto alloc = [&](size_t bytes) {
        void* q = p; p += (bytes + 255) & ~(size_t)255; return q;
    };
    float* x   = (float*)alloc((size_t)NT_ * D_ * 4);
    bf16*  xb  = (bf16*) alloc((size_t)NT_ * D_ * 2);
    bf16*  q_  = (bf16*) alloc((size_t)NT_ * D_ * 2);
    bf16*  k_  = (bf16*) alloc((size_t)NT_ * D_ * 2);
    bf16*  v_  = (bf16*) alloc((size_t)NT_ * D_ * 2);
    bf16*  vT  = (bf16*) alloc((size_t)NT_ * D_ * 2);
    bf16*  y_  = (bf16*) alloc((size_t)NT_ * D_ * 2);
    bf16*  hln = (bf16*) alloc((size_t)NT_ * D_ * 2);
    bf16*  h1  = (bf16*) alloc((size_t)NT_ * DFF_ * 2);
    float* sc  = (float*)alloc((size_t)B_ * H_ * S_ * S_ * 4);
    bf16*  P   = (bf16*) alloc((size_t)B_ * H_ * S_ * S_ * 2);
    bf16*  wqT = (bf16*) alloc((size_t)D_ * D_ * 2);
    bf16*  wkT = (bf16*) alloc((size_t)D_ * D_ * 2);
    bf16*  wvT = (bf16*) alloc((size_t)D_ * D_ * 2);
    bf16*  woT = (bf16*) alloc((size_t)D_ * D_ * 2);
    bf16*  w1T = (bf16*) alloc((size_t)D_ * DFF_ * 2);
    bf16*  w2T = (bf16*) alloc((size_t)D_ * DFF_ * 2);
    bf16*  teB = (bf16*) alloc((size_t)V_ * D_ * 2);

    if ((size_t)(p - (char*)d_ws) > ws_size) {
        ws_fail_kernel<<<1, 1, 0, stream>>>(logits);   // sentinel: ws too small
        return;
    }

    // te -> bf16 (no transpose: te is already [N=V, K=D])
    {
        const long long n = (long long)V_ * D_;
        conv_bf16<<<dim3((unsigned)((n / 4 + 255) / 256)), 256, 0, stream>>>(te, teB, n);
    }
    embed_kernel<<<NT_, 64, 0, stream>>>(idx, te, pe, x, xb);

    const long long ZA = (long long)S_ * D_;       // per-b stride in q/k/y
    const long long ZS = (long long)S_ * S_;       // per-head score stride

    for (int l = 0; l < L_; l++) {
        convT<<<dim3(32, 32), 256, 0, stream>>>(wq + (size_t)l * D_ * D_, wqT, D_, D_);
        convT<<<dim3(32, 32), 256, 0, stream>>>(wk + (size_t)l * D_ * D_, wkT, D_, D_);
        convT<<<dim3(32, 32), 256, 0, stream>>>(wv + (size_t)l * D_ * D_, wvT, D_, D_);
        convT<<<dim3(32, 32), 256, 0, stream>>>(wo + (size_t)l * D_ * D_, woT, D_, D_);
        convT<<<dim3(DFF_ / 32, 32), 256, 0, stream>>>(w1 + (size_t)l * D_ * DFF_, w1T, D_, DFF_);
        convT<<<dim3(32, DFF_ / 32), 256, 0, stream>>>(w2 + (size_t)l * DFF_ * D_, w2T, DFF_, D_);

        // q/k/v = xb @ W^T + b   -> bf16 [B,S,D]
        gemm_bt<128,128><<<dim3(8, 16, 1), 256, 0, stream>>>(
            xb, D_, 0, 0, wqT, D_, 0, 0, bq + l * D_, 1.f, nullptr, 0,
            nullptr, 0, 0, 0, q_, D_, 0, 0, NT_, D_, D_, 1, 0, 0, 0);
        gemm_bt<128,128><<<dim3(8, 16, 1), 256, 0, stream>>>(
            xb, D_, 0, 0, wkT, D_, 0, 0, bk + l * D_, 1.f, nullptr, 0,
            nullptr, 0, 0, 0, k_, D_, 0, 0, NT_, D_, D_, 1, 0, 0, 0);
        gemm_bt<128,128><<<dim3(8, 16, 1), 256, 0, stream>>>(
            xb, D_, 0, 0, wvT, D_, 0, 0, bv + l * D_, 1.f, nullptr, 0,
            nullptr, 0, 0, 0, v_, D_, 0, 0, NT_, D_, D_, 1, 0, 0, 0);

        transpose_v<<<dim3(S_ / 32, DK_ / 32, B_ * H_), 256, 0, stream>>>(v_, vT);

        // scores[b,h] = q[b,:,h,:] @ k[b,:,h,:]^T * 1/8  (causal tiles skipped)
        gemm_bt<128,128><<<dim3(8, 8, B_ * H_), 256, 0, stream>>>(
            q_, D_, ZA, DK_, k_, D_, ZA, DK_, nullptr, 0.125f, nullptr, 0,
            sc, S_, (long long)H_ * ZS, ZS, nullptr, 0, 0, 0,
            S_, S_, DK_, H_, 0, 1, 0);

        softmax_kernel<<<dim3(S_, B_ * H_), 64, 0, stream>>>(sc, P);

        // y[b,:,h,:] = P[b,h] @ v[b,:,h,:]
        gemm_bt<128,64><<<dim3(1, 8, B_ * H_), 256, 0, stream>>>(
            P, S_, (long long)H_ * ZS, ZS, vT, S_, (long long)H_ * DK_ * S_, (long long)DK_ * S_,
            nullptr, 1.f, nullptr, 0, nullptr, 0, 0, 0,
            y_, D_, ZA, DK_, S_, DK_, S_, H_, 0, 0, 0);

        // x += y @ wo^T + bo   (fp32 out, in-place residual)
        gemm_bt<128,128><<<dim3(8, 16, 1), 256, 0, stream>>>(
            y_, D_, 0, 0, woT, D_, 0, 0, bo + l * D_, 1.f, x, D_,
            x, D_, 0, 0, nullptr, 0, 0, 0, NT_, D_, D_, 1, 0, 0, 0);

        layernorm_kernel<<<NT_, 64, 0, stream>>>(x, ln2g + l * D_, ln2b + l * D_, hln);

        // h1 = gelu(hln @ w1 + b1)  -> bf16
        gemm_bt<128,128><<<dim3(DFF_ / 128, 16, 1), 256, 0, stream>>>(
            hln, D_, 0, 0, w1T, D_, 0, 0, b1 + l * DFF_, 1.f, nullptr, 0,
            nullptr, 0, 0, 0, h1, DFF_, 0, 0, NT_, DFF_, D_, 1, 1, 0, 0);

        // x += h1 @ w2 + b2 ; also refresh xb (bf16 copy of x)
        gemm_bt<128,128><<<dim3(8, 16, 1), 256, 0, stream>>>(
            h1, DFF_, 0, 0, w2T, DFF_, 0, 0, b2 + l * D_, 1.f, x, D_,
            x, D_, 0, 0, xb, D_, 0, 0, NT_, D_, DFF_, 1, 0, 0, 0);
    }

    layernorm_kernel<<<NT_, 64, 0, stream>>>(x, lnfg, lnfb, hln);

    // logits = lnf(x) @ te^T   (fp32 out, N = 50257 with row clamp + store guard)
    // swapxy=1: m-fastest raster so the ~256 concurrent blocks cover 16m x 16n
    // -> each teB panel (103 MB total) is read once and reused from cache.
    gemm_bt<128,128><<<dim3(16, (V_ + 127) / 128, 1), 256, 0, stream>>>(
        hln, D_, 0, 0, teB, D_, 0, 0, nullptr, 1.f, nullptr, 0,
        logits, V_, 0, 0, nullptr, 0, 0, 0, NT_, V_, D_, 1, 0, 0, 1);
}

// Round 3
// 2258.304 us; speedup vs baseline: 1.4914x; 1.2155x over previous
//
#include <hip/hip_runtime.h>
#include <hip/hip_bf16.h>
#include <math.h>

#define D_   1024
#define H_   16
#define V_   50257
#define L_   4
#define B_   2
#define S_   1024
#define DK_  64
#define DFF_ 4096
#define NT_  (B_*S_)   // 2048 tokens

using bf16 = __hip_bfloat16;
typedef __attribute__((ext_vector_type(8))) __bf16 bf16x8;
typedef __attribute__((ext_vector_type(4))) float  f32x4;

// async global->LDS, 16B per lane; LDS dest is wave-uniform base + lane*16
__device__ __forceinline__ void gload_lds16(const void* g, void* l)
{
    __builtin_amdgcn_global_load_lds(
        (const __attribute__((address_space(1))) unsigned int*)g,
        (__attribute__((address_space(3))) unsigned int*)l, 16, 0, 0);
}

// ---------------------------------------------------------------------------
// Generic bf16 GEMM: C[M,N] = A[M,K] @ B^T  (B stored [N,K] row-major).
// raster: 0 = x->n, y->m (normal); 1 = x->m, y->n (B-panel reuse for wide N);
//         2 = raster 1 + chunked bijective XCD swizzle (m204): each XCD gets
//             a contiguous m-fastest run so all m-blocks of a B-panel share
//             one XCD L2 (panel fetched once per L2, not 8x).
// kclip: K_use = min(K, m0+BM) — for PV where P[m,k]=0 beyond k >= m0+BM.
// Staging: global_load_lds dwordx4 into LINEAR LDS [rows][32] bf16 (m97).
// Fragment layouts (learn_hip m89/m91/m97):
//   A-frag:  lane holds A[m = lane&15][k = (lane>>4)*8 + j]
//   B-frag:  lane holds B[n = lane&15][k = (lane>>4)*8 + j]   (B^T layout)
//   C/D:     col = lane&15, row = (lane>>4)*4 + reg
// Waves: 2x2 layout; per-wave sub-tile (BM/2)x(BN/2).
// Requires: M % BM == 0, K % 32 == 0 (N tail handled by clamp + store guard).
// ---------------------------------------------------------------------------
template<int BM, int BN>
__global__ __launch_bounds__(256) void gemm_bt(
    const bf16* __restrict__ A, int lda, long long sA1, long long sA2,
    const bf16* __restrict__ Bm, int ldb, long long sB1, long long sB2,
    const float* __restrict__ bias, float scale,
    const float* __restrict__ Rz, int ldr,
    float* __restrict__ CF, int ldcF, long long sCF1, long long sCF2,
    bf16* __restrict__ CB, int ldcB, long long sCB1, long long sCB2,
    int M, int N, int K, int bz2, int gelu_f, int causal, int raster, int kclip)
{
    int bx = blockIdx.x, by = blockIdx.y;
    if (raster) {
        unsigned mi = bx, ni = by;           // raster>=1 launch: x indexes m, y indexes n
        if (raster == 2) {
            const unsigned nwg = gridDim.x * gridDim.y;
            const unsigned lin = by * gridDim.x + bx;   // dispatch-linear (x fastest)
            const unsigned q = nwg >> 3, r = nwg & 7;
            const unsigned xcd = lin & 7, pos = lin >> 3;
            const unsigned nid = (xcd < r) ? xcd * (q + 1) + pos
                                           : r * (q + 1) + (xcd - r) * q + pos;
            mi = nid % gridDim.x;
            ni = nid / gridDim.x;
        }
        bx = ni; by = mi;
    }
    const int m0 = by * BM;
    const int n0 = bx * BN;
    if (causal && n0 > m0 + BM - 1) return;   // fully-masked score tile, never read

    const int z  = blockIdx.z;
    const int b1 = z / bz2, b2 = z % bz2;
    A  += (long long)b1 * sA1 + (long long)b2 * sA2;
    Bm += (long long)b1 * sB1 + (long long)b2 * sB2;
    const long long cfoff = (long long)b1 * sCF1 + (long long)b2 * sCF2;
    const long long cboff = (long long)b1 * sCB1 + (long long)b2 * sCB2;

    int K_use = K;
    if (kclip) { const int kk = m0 + BM; K_use = kk < K ? kk : K; }

    // linear LDS: rows of 32 bf16 (64 B). global_load_lds writes base+lane*16.
    __shared__ __align__(16) bf16 As[BM * 32];
    __shared__ __align__(16) bf16 Bs[BN * 32];

    const int tid  = threadIdx.x;
    const int lane = tid & 63;
    const int wave = tid >> 6;
    const int wm = (wave >> 1) * (BM / 2);
    const int wn = (wave & 1) * (BN / 2);
    constexpr int WM = (BM / 2) / 16;
    constexpr int WN = (BN / 2) / 16;

    f32x4 acc[WM][WN] = {};

    const int lm = lane & 15;
    const int lk = (lane >> 4) * 8;

    // staging geometry: one wave-call covers 1024 B = 16 rows x 64 B.
    // lane i -> row (i>>2) within chunk, byte col (i&3)*16.
    const int lrow  = lane >> 2;         // 0..15
    const int lcolb = (lane & 3) * 16;   // 0/16/32/48 bytes

    constexpr int CA  = BM / 16 / 4;     // A chunks per wave
    constexpr int CB_ = BN / 16 / 4;     // B chunks per wave

    for (int k0 = 0; k0 < K_use; k0 += 32) {
        #pragma unroll
        for (int it = 0; it < CA; it++) {
            const int c = wave + it * 4;
            const char* src = (const char*)(A + (long long)(m0 + c * 16 + lrow) * lda + k0) + lcolb;
            gload_lds16(src, &As[c * 16 * 32]);
        }
        #pragma unroll
        for (int it = 0; it < CB_; it++) {
            const int c = wave + it * 4;
            int rr = n0 + c * 16 + lrow; rr = rr < N ? rr : N - 1;   // clamp (head: V=50257)
            const char* src = (const char*)(Bm + (long long)rr * ldb + k0) + lcolb;
            gload_lds16(src, &Bs[c * 16 * 32]);
        }
        __syncthreads();   // compiler emits s_waitcnt vmcnt(0) before s_barrier

        bf16x8 af[WM], bfr[WN];
        #pragma unroll
        for (int i = 0; i < WM; i++)
            af[i] = *(const bf16x8*)&As[(wm + i * 16 + lm) * 32 + lk];
        #pragma unroll
        for (int j = 0; j < WN; j++)
            bfr[j] = *(const bf16x8*)&Bs[(wn + j * 16 + lm) * 32 + lk];

        #pragma unroll
        for (int i = 0; i < WM; i++)
            #pragma unroll
            for (int j = 0; j < WN; j++)
                acc[i][j] = __builtin_amdgcn_mfma_f32_16x16x32_bf16(
                    af[i], bfr[j], acc[i][j], 0, 0, 0);
        __syncthreads();
    }

    const int rmb = (lane >> 4) << 2;
    #pragma unroll
    for (int i = 0; i < WM; i++) {
        #pragma unroll
        for (int j = 0; j < WN; j++) {
            const int n = n0 + wn + j * 16 + lm;
            if (n >= N) continue;
            const float bv = bias ? bias[n] : 0.0f;
            #pragma unroll
            for (int r = 0; r < 4; r++) {
                const int m = m0 + wm + i * 16 + rmb + r;
                float v = acc[i][j][r] * scale + bv;
                if (gelu_f) v = 0.5f * v * (1.0f + erff(v * 0.70710678118654752f));
                if (Rz) v += Rz[(long long)m * ldr + n];
                if (CF) CF[cfoff + (long long)m * ldcF + n] = v;
                if (CB) CB[cboff + (long long)m * ldcB + n] = __float2bfloat16(v);
            }
        }
    }
}

// fp32 [K,N] -> bf16 [N,K] (convert + transpose), dims multiples of 32
__global__ __launch_bounds__(256) void convT(const float* __restrict__ in,
                                             bf16* __restrict__ out, int K, int N)
{
    __shared__ float tile[32][33];
    const int bx = blockIdx.x * 32;   // N
    const int by = blockIdx.y * 32;   // K
    const int tx = threadIdx.x & 31, ty = threadIdx.x >> 5;
    #pragma unroll
    for (int i = 0; i < 32; i += 8)
        tile[ty + i][tx] = in[(long long)(by + ty + i) * N + bx + tx];
    __syncthreads();
    #pragma unroll
    for (int i = 0; i < 32; i += 8)
        out[(long long)(bx + ty + i) * K + by + tx] = __float2bfloat16(tile[tx][ty + i]);
}

// fp32 -> bf16 elementwise (n % 4 == 0)
__global__ __launch_bounds__(256) void conv_bf16(const float* __restrict__ in,
                                                 bf16* __restrict__ out, long long n)
{
    const long long i = ((long long)blockIdx.x * 256 + threadIdx.x) * 4;
    if (i >= n) return;
    const float4 v = *(const float4*)&in[i];
    union { bf16 h[4]; uint2 u; } o;
    o.h[0] = __float2bfloat16(v.x); o.h[1] = __float2bfloat16(v.y);
    o.h[2] = __float2bfloat16(v.z); o.h[3] = __float2bfloat16(v.w);
    *(uint2*)&out[i] = o.u;
}

// concat 3 x [D_] fp32 -> [3*D_]
__global__ __launch_bounds__(256) void concat3(const float* __restrict__ a,
    const float* __restrict__ b, const float* __restrict__ c, float* __restrict__ o)
{
    const int i = blockIdx.x * 256 + threadIdx.x;
    if (i < D_) { o[i] = a[i]; o[D_ + i] = b[i]; o[2 * D_ + i] = c[i]; }
}

// v [B,S,ldv] bf16 (head-interleaved at offset) -> vT [B*H, DK, S] bf16
__global__ __launch_bounds__(256) void transpose_v(const bf16* __restrict__ v, int ldv,
                                                   bf16* __restrict__ vT)
{
    __shared__ bf16 tile[32][33];
    const int bh = blockIdx.z;
    const int b = bh >> 4, h = bh & 15;
    const int s0 = blockIdx.x * 32, d0 = blockIdx.y * 32;
    const int tx = threadIdx.x & 31, ty = threadIdx.x >> 5;
    const bf16* src = v + (long long)b * S_ * ldv + h * DK_;
    #pragma unroll
    for (int i = 0; i < 32; i += 8)
        tile[ty + i][tx] = src[(long long)(s0 + ty + i) * ldv + d0 + tx];
    __syncthreads();
    bf16* dst = vT + (long long)bh * DK_ * S_;
    #pragma unroll
    for (int i = 0; i < 32; i += 8)
        dst[(long long)(d0 + ty + i) * S_ + s0 + tx] = tile[tx][ty + i];
}

// x[t] = te[idx[t]] + pe[t % S]; writes fp32 x and bf16 xb
__global__ __launch_bounds__(64) void embed_kernel(const int* __restrict__ idx,
    const float* __restrict__ te, const float* __restrict__ pe,
    float* __restrict__ x, bf16* __restrict__ xb)
{
    const int t = blockIdx.x;
    const int s = t & (S_ - 1);
    const int id = idx[t];
    const float* tr = te + (long long)id * D_;
    const float* pr = pe + (long long)s * D_;
    float* xr  = x  + (long long)t * D_;
    bf16*  xbr = xb + (long long)t * D_;
    for (int i = threadIdx.x * 4; i < D_; i += 256) {
        const float4 a = *(const float4*)&tr[i];
        const float4 b = *(const float4*)&pr[i];
        const float4 c = {a.x + b.x, a.y + b.y, a.z + b.z, a.w + b.w};
        *(float4*)&xr[i] = c;
        union { bf16 h[4]; uint2 u; } o;
        o.h[0] = __float2bfloat16(c.x); o.h[1] = __float2bfloat16(c.y);
        o.h[2] = __float2bfloat16(c.z); o.h[3] = __float2bfloat16(c.w);
        *(uint2*)&xbr[i] = o.u;
    }
}

// one wave per row: bf16 layernorm(x fp32) -> out bf16
__global__ __launch_bounds__(64) void layernorm_kernel(const float* __restrict__ x,
    const float* __restrict__ g, const float* __restrict__ b, bf16* __restrict__ out)
{
    const int row = blockIdx.x;
    const float* xr = x + (long long)row * D_;
    float s = 0.f, ss = 0.f;
    for (int i = threadIdx.x * 4; i < D_; i += 256) {
        const float4 v = *(const float4*)&xr[i];
        s  += v.x + v.y + v.z + v.w;
        ss += v.x * v.x + v.y * v.y + v.z * v.z + v.w * v.w;
    }
    #pragma unroll
    for (int off = 32; off; off >>= 1) {
        s  += __shfl_down(s, off);
        ss += __shfl_down(ss, off);
    }
    s = __shfl(s, 0); ss = __shfl(ss, 0);
    const float mean = s * (1.0f / D_);
    const float var  = ss * (1.0f / D_) - mean * mean;
    const float rstd = rsqrtf(var + 1e-5f);
    bf16* orow = out + (long long)row * D_;
    for (int i = threadIdx.x * 4; i < D_; i += 256) {
        const float4 v = *(const float4*)&xr[i];
        union { bf16 h[4]; uint2 u; } o;
        o.h[0] = __float2bfloat16((v.x - mean) * rstd * g[i]     + b[i]);
        o.h[1] = __float2bfloat16((v.y - mean) * rstd * g[i + 1] + b[i + 1]);
        o.h[2] = __float2bfloat16((v.z - mean) * rstd * g[i + 2] + b[i + 2]);
        o.h[3] = __float2bfloat16((v.w - mean) * rstd * g[i + 3] + b[i + 3]);
        *(uint2*)&orow[i] = o.u;
    }
}

// one wave per (bh, sq) row: causal softmax, fp32 scores -> bf16 P.
// Writes only k < (sq&~127)+128 — exactly the range the kclip'd PV reads.
__global__ __launch_bounds__(64) void softmax_kernel(const float* __restrict__ sc,
                                                     bf16* __restrict__ P)
{
    const int sq = blockIdx.x;
    const long long base = ((long long)blockIdx.y * S_ + sq) * S_;
    const float* row = sc + base;
    bf16* prow = P + base;
    const int lane = threadIdx.x;
    const int len = sq + 1;
    const int lim = (sq & ~127) + 128;
    float mx = -3.0e38f;
    for (int i = lane; i < len; i += 64) mx = fmaxf(mx, row[i]);
    #pragma unroll
    for (int off = 32; off; off >>= 1) mx = fmaxf(mx, __shfl_down(mx, off));
    mx = __shfl(mx, 0);
    float sum = 0.f;
    for (int i = lane; i < len; i += 64) sum += __expf(row[i] - mx);
    #pragma unroll
    for (int off = 32; off; off >>= 1) sum += __shfl_down(sum, off);
    sum = __shfl(sum, 0);
    const float inv = 1.0f / sum;
    for (int i = lane; i < lim; i += 64) {
        const float pv = (i < len) ? __expf(row[i] - mx) * inv : 0.f;
        prow[i] = __float2bfloat16(pv);
    }
}

__global__ void ws_fail_kernel(float* out) { out[0] = 12345.0f; }

extern "C" void kernel_launch(void* const* d_in, const int* in_sizes, int n_in,
                              void* d_out, int out_size, void* d_ws, size_t ws_size,
                              hipStream_t stream)
{
    const int*   idx  = (const int*)  d_in[0];
    const float* te   = (const float*)d_in[1];
    const float* pe   = (const float*)d_in[2];
    const float* wq   = (const float*)d_in[3];
    const float* bq   = (const float*)d_in[4];
    const float* wk   = (const float*)d_in[5];
    const float* bk   = (const float*)d_in[6];
    const float* wv   = (const float*)d_in[7];
    const float* bv   = (const float*)d_in[8];
    const float* wo   = (const float*)d_in[9];
    const float* bo   = (const float*)d_in[10];
    const float* ln2g = (const float*)d_in[11];
    const float* ln2b = (const float*)d_in[12];
    const float* w1   = (const float*)d_in[13];
    const float* b1   = (const float*)d_in[14];
    const float* w2   = (const float*)d_in[15];
    const float* b2   = (const float*)d_in[16];
    const float* lnfg = (const float*)d_in[17];
    const float* lnfb = (const float*)d_in[18];
    float* logits = (float*)d_out;

    char* p = (char*)d_ws;
    auto alloc = [&](size_t bytes) {
        void* q = p; p += (bytes + 255) & ~(size_t)255; return q;
    };
    float* x    = (float*)alloc((size_t)NT_ * D_ * 4);
    bf16*  xb   = (bf16*) alloc((size_t)NT_ * D_ * 2);
    bf16*  qkv  = (bf16*) alloc((size_t)NT_ * 3 * D_ * 2);   // [NT, 3D] fused q|k|v
    bf16*  vT   = (bf16*) alloc((size_t)NT_ * D_ * 2);
    bf16*  y_   = (bf16*) alloc((size_t)NT_ * D_ * 2);
    bf16*  hln  = (bf16*) alloc((size_t)NT_ * D_ * 2);
    bf16*  h1   = (bf16*) alloc((size_t)NT_ * DFF_ * 2);
    float* sc   = (float*)alloc((size_t)B_ * H_ * S_ * S_ * 4);
    bf16*  P    = (bf16*) alloc((size_t)B_ * H_ * S_ * S_ * 2);
    bf16*  wqkvT= (bf16*) alloc((size_t)3 * D_ * D_ * 2);    // wqT|wkT|wvT contiguous
    bf16*  woT  = (bf16*) alloc((size_t)D_ * D_ * 2);
    bf16*  w1T  = (bf16*) alloc((size_t)D_ * DFF_ * 2);
    bf16*  w2T  = (bf16*) alloc((size_t)D_ * DFF_ * 2);
    bf16*  teB  = (bf16*) alloc((size_t)V_ * D_ * 2);
    float* bqkv = (float*)alloc((size_t)3 * D_ * 4);

    if ((size_t)(p - (char*)d_ws) > ws_size) {
        ws_fail_kernel<<<1, 1, 0, stream>>>(logits);   // sentinel: ws too small
        return;
    }

    bf16* wqT = wqkvT;
    bf16* wkT = wqkvT + (size_t)D_ * D_;
    bf16* wvT = wqkvT + (size_t)2 * D_ * D_;
    bf16* q_  = qkv;
    bf16* k_  = qkv + D_;
    bf16* v_  = qkv + 2 * D_;
    const int ldq = 3 * D_;

    // te -> bf16 (no transpose: te is already [N=V, K=D])
    {
        const long long n = (long long)V_ * D_;
        conv_bf16<<<dim3((unsigned)((n / 4 + 255) / 256)), 256, 0, stream>>>(te, teB, n);
    }
    embed_kernel<<<NT_, 64, 0, stream>>>(idx, te, pe, x, xb);

    const long long ZAQ = (long long)S_ * ldq;     // per-b stride in fused qkv
    const long long ZA  = (long long)S_ * D_;      // per-b stride in y
    const long long ZS  = (long long)S_ * S_;      // per-head score stride

    for (int l = 0; l < L_; l++) {
        convT<<<dim3(32, 32), 256, 0, stream>>>(wq + (size_t)l * D_ * D_, wqT, D_, D_);
        convT<<<dim3(32, 32), 256, 0, stream>>>(wk + (size_t)l * D_ * D_, wkT, D_, D_);
        convT<<<dim3(32, 32), 256, 0, stream>>>(wv + (size_t)l * D_ * D_, wvT, D_, D_);
        convT<<<dim3(32, 32), 256, 0, stream>>>(wo + (size_t)l * D_ * D_, woT, D_, D_);
        convT<<<dim3(DFF_ / 32, 32), 256, 0, stream>>>(w1 + (size_t)l * D_ * DFF_, w1T, D_, DFF_);
        convT<<<dim3(32, DFF_ / 32), 256, 0, stream>>>(w2 + (size_t)l * DFF_ * D_, w2T, DFF_, D_);
        concat3<<<dim3(4), 256, 0, stream>>>(bq + (size_t)l * D_, bk + (size_t)l * D_,
                                             bv + (size_t)l * D_, bqkv);

        // fused qkv = xb @ [wq|wk|wv]^T + [bq|bk|bv]  -> bf16 [NT, 3D]
        // BM=64: grid (24,32)=768 blocks, full machine fill
        gemm_bt<64,128><<<dim3(24, 32, 1), 256, 0, stream>>>(
            xb, D_, 0, 0, wqkvT, D_, 0, 0, bqkv, 1.f, nullptr, 0,
            nullptr, 0, 0, 0, qkv, ldq, 0, 0, NT_, 3 * D_, D_, 1, 0, 0, 0, 0);

        transpose_v<<<dim3(S_ / 32, DK_ / 32, B_ * H_), 256, 0, stream>>>(v_, ldq, vT);

        // scores[b,h] = q[b,:,h,:] @ k[b,:,h,:]^T * 1/8  (causal tiles skipped)
        gemm_bt<128,128><<<dim3(8, 8, B_ * H_), 256, 0, stream>>>(
            q_, ldq, ZAQ, DK_, k_, ldq, ZAQ, DK_, nullptr, 0.125f, nullptr, 0,
            sc, S_, (long long)H_ * ZS, ZS, nullptr, 0, 0, 0,
            S_, S_, DK_, H_, 0, 1, 0, 0);

        softmax_kernel<<<dim3(S_, B_ * H_), 64, 0, stream>>>(sc, P);

        // y[b,:,h,:] = P[b,h] @ v[b,:,h,:]   (kclip: only k < m0+128 is nonzero)
        gemm_bt<128,64><<<dim3(1, 8, B_ * H_), 256, 0, stream>>>(
            P, S_, (long long)H_ * ZS, ZS, vT, S_, (long long)H_ * DK_ * S_, (long long)DK_ * S_,
            nullptr, 1.f, nullptr, 0, nullptr, 0, 0, 0,
            y_, D_, ZA, DK_, S_, DK_, S_, H_, 0, 0, 0, 1);

        // x += y @ wo^T + bo   (fp32 out, in-place residual); BM=64 -> 256 blocks
        gemm_bt<64,128><<<dim3(8, 32, 1), 256, 0, stream>>>(
            y_, D_, 0, 0, woT, D_, 0, 0, bo + l * D_, 1.f, x, D_,
            x, D_, 0, 0, nullptr, 0, 0, 0, NT_, D_, D_, 1, 0, 0, 0, 0);

        layernorm_kernel<<<NT_, 64, 0, stream>>>(x, ln2g + l * D_, ln2b + l * D_, hln);

        // h1 = gelu(hln @ w1 + b1)  -> bf16 ; 512 blocks, keep 128^2
        gemm_bt<128,128><<<dim3(DFF_ / 128, 16, 1), 256, 0, stream>>>(
            hln, D_, 0, 0, w1T, D_, 0, 0, b1 + l * DFF_, 1.f, nullptr, 0,
            nullptr, 0, 0, 0, h1, DFF_, 0, 0, NT_, DFF_, D_, 1, 1, 0, 0, 0);

        // x += h1 @ w2 + b2 ; also refresh xb (bf16 copy of x); BM=64 -> 256 blocks
        gemm_bt<64,128><<<dim3(8, 32, 1), 256, 0, stream>>>(
            h1, DFF_, 0, 0, w2T, DFF_, 0, 0, b2 + l * D_, 1.f, x, D_,
            x, D_, 0, 0, xb, D_, 0, 0, NT_, D_, DFF_, 1, 0, 0, 0, 0);
    }

    layernorm_kernel<<<NT_, 64, 0, stream>>>(x, lnfg, lnfb, hln);

    // logits = lnf(x) @ te^T   (fp32 out, N = 50257 with row clamp + store guard)
    // raster=2: m-fastest + chunked XCD swizzle -> each teB panel lives in ONE
    // XCD L2 and is reused by all 16 m-blocks (nwg = 16*393 = 6288, 6288%8==0).
    gemm_bt<128,128><<<dim3(16, (V_ + 127) / 128, 1), 256, 0, stream>>>(
        hln, D_, 0, 0, teB, D_, 0, 0, nullptr, 1.f, nullptr, 0,
        logits, V_, 0, 0, nullptr, 0, 0, 0, NT_, V_, D_, 1, 0, 0, 2, 0);
}